// Round 3
// baseline (203.110 us; speedup 1.0000x reference)
//
#include <hip/hip_runtime.h>
#include <cstdint>
#include <cstddef>

#define BS 32
#define NA 8400
#define NM 64
#define NPRO 31
#define NALP 24
#define NADS 37
#define TOPK 13
#define FEPS 1e-9f
#define WORDS 264   // ceil(8400/32)=263, padded
#define CAP 1024    // compact positive-metric list capacity (expected max ~400)
#define TL 16       // per-(b,m) topk list slots: [0]=count, [1..13]=anchor ids

// output offsets (floats), concatenated in reference return order
#define OFF0 0L          // target_pro      (32,8400)
#define OFF1 268800L     // target_alp      (32,8400)
#define OFF2 537600L     // target_ad0_4    (5,32,8400)
#define OFF3 1881600L    // target_bboxes   (32,8400,4)
#define OFF4 2956800L    // target_corners  (32,8400,8)
#define OFF5 5107200L    // pro_scores      (32,8400,31)
#define OFF6 13440000L   // alp_scores      (32,8400,24)
#define OFF7 19891200L   // ads_scores      (5,32,8400,37)
#define OFF8 69619200L   // fg_mask         (32,8400)

typedef float f4_t __attribute__((ext_vector_type(4)));

__device__ __forceinline__ void nt4(float* p, float a, float b, float c, float d) {
  f4_t v = {a, b, c, d};
  __builtin_nontemporal_store(v, (f4_t*)p);
}
__device__ __forceinline__ void nt1(float* p, float v) {
  __builtin_nontemporal_store(v, p);
}

__device__ __forceinline__ float iou1(float4 g, float ga, float4 p, float pa) {
  float iw = fmaxf(fminf(g.z, p.z) - fmaxf(g.x, p.x), 0.f);
  float ih = fmaxf(fminf(g.w, p.w) - fmaxf(g.y, p.y), 0.f);
  float inter = iw * ih;
  return inter / (ga + pa - inter + FEPS);
}

// ---------------- kA: per-(b,m) sparse metrics + exact top-13 -> compact list ----------------
__global__ __launch_bounds__(256) void kA(
    const float* __restrict__ pro, const float* __restrict__ pd_bb,
    const float* __restrict__ anc, const int* __restrict__ gt_pro,
    const float* __restrict__ gt_bb, const float* __restrict__ mask_gt,
    short* __restrict__ tlist, unsigned* __restrict__ posA,
    unsigned* __restrict__ posO)
{
  __shared__ unsigned s_in[WORDS];   // in-box bits
  __shared__ unsigned s_pos[WORDS];  // positive-metric bits
  __shared__ float s_cv[CAP];
  __shared__ int   s_ci[CAP];
  __shared__ int   s_cnt;

  const int bm = blockIdx.x;
  const int b = bm >> 6;
  const int tid = threadIdx.x;

  if (tid == 0) { posA[bm] = 0u; posO[bm] = 0u; }

  short* tl = tlist + bm * TL;
  if (!(mask_gt[bm] > 0.f)) {        // invalid gt -> no selections (counts>1 trick)
    if (tid == 0) tl[0] = 0;
    return;
  }

  for (int w = tid; w < WORDS; w += 256) { s_in[w] = 0u; s_pos[w] = 0u; }
  if (tid == 0) s_cnt = 0;
  __syncthreads();

  const float4 g = *(const float4*)(gt_bb + (size_t)bm * 4);
  const int label = gt_pro[bm];
  const float ga = fmaxf(g.z - g.x, 0.f) * fmaxf(g.w - g.y, 0.f);
  const float* pb = pd_bb + (size_t)b * NA * 4;
  const float* ps = pro + (size_t)b * NA * NPRO + label;

  for (int a = tid; a < NA; a += 256) {
    float2 ap = *(const float2*)(anc + 2 * a);
    float din = fminf(fminf(ap.x - g.x, ap.y - g.y), fminf(g.z - ap.x, g.w - ap.y));
    if (din > FEPS) {
      atomicOr(&s_in[a >> 5], 1u << (a & 31));
      float4 p = *(const float4*)(pb + (size_t)a * 4);
      float pa = fmaxf(p.z - p.x, 0.f) * fmaxf(p.w - p.y, 0.f);
      float iou = iou1(g, ga, p, pa);
      float i2 = iou * iou;
      float met = ps[(size_t)a * NPRO] * (i2 * i2 * i2);
      if (met > 0.f) {
        atomicOr(&s_pos[a >> 5], 1u << (a & 31));
        int pidx = atomicAdd(&s_cnt, 1);
        if (pidx < CAP) { s_cv[pidx] = met; s_ci[pidx] = a; }
      }
    }
  }
  __syncthreads();

  const int P = min(s_cnt, CAP);
  if (tid < 64) {
    // each lane owns entries tid, tid+64, ... in registers
    float lv[16]; int li[16];
#pragma unroll
    for (int e = 0; e < 16; e++) {
      int p = tid + e * 64;
      bool ok = p < P;
      lv[e] = ok ? s_cv[p] : -1.f;
      li[e] = ok ? s_ci[p] : NA;
    }
    const int nsel = min(P, TOPK);
    for (int k = 0; k < nsel; k++) {
      float bv = -1.f; int bi = NA;
#pragma unroll
      for (int e = 0; e < 16; e++)
        if (lv[e] > bv || (lv[e] == bv && li[e] < bi)) { bv = lv[e]; bi = li[e]; }
      for (int s = 1; s < 64; s <<= 1) {
        float ov = __shfl_xor(bv, s);
        int   oi = __shfl_xor(bi, s);
        if (ov > bv || (ov == bv && oi < bi)) { bv = ov; bi = oi; }
      }
#pragma unroll
      for (int e = 0; e < 16; e++) if (li[e] == bi) lv[e] = -1.f;  // clear winner
      if (tid == 0) tl[1 + k] = (short)bi;
    }
    if (tid == 0) {
      int cnt = nsel;
      if (P < TOPK) {
        // fill remaining slots with lowest-index zero-metric anchors (tie at 0),
        // keeping only in-box ones (mask_in AND)
        int need = TOPK - P;
        for (int a = 0; a < NA && need > 0; a++) {
          if (!((s_pos[a >> 5] >> (a & 31)) & 1u)) {
            need--;
            if ((s_in[a >> 5] >> (a & 31)) & 1u) tl[1 + cnt++] = (short)a;
          }
        }
      }
      tl[0] = (short)cnt;
    }
  }
}

// ---------------- kB: per-anchor resolve from compact lists ----------------
__global__ __launch_bounds__(256) void kB(
    const float* __restrict__ pro, const float* __restrict__ pd_bb,
    const int* __restrict__ gt_pro, const float* __restrict__ gt_bb,
    const short* __restrict__ tlist,
    unsigned* __restrict__ posA, unsigned* __restrict__ posO,
    int* __restrict__ tgi, float* __restrict__ fgo, float* __restrict__ avo)
{
  __shared__ float4 s_g[NM];
  __shared__ float s_ga[NM];
  __shared__ int s_lab[NM];
  __shared__ unsigned long long s_m[256];
  __shared__ short s_tl[NM * TL];

  const int b = blockIdx.y;
  const int a0 = blockIdx.x << 8;
  const int tid = threadIdx.x;

  s_m[tid] = 0ull;
  if (tid < NM) {
    float4 gg = *(const float4*)(gt_bb + (size_t)(b * NM + tid) * 4);
    s_g[tid] = gg;
    s_ga[tid] = fmaxf(gg.z - gg.x, 0.f) * fmaxf(gg.w - gg.y, 0.f);
    s_lab[tid] = gt_pro[b * NM + tid];
  }
  for (int i = tid; i < NM * TL / 2; i += 256)       // 512 ints = 1024 shorts
    ((int*)s_tl)[i] = ((const int*)(tlist + (size_t)b * NM * TL))[i];
  __syncthreads();

  for (int i = tid; i < NM * TL; i += 256) {
    int m = i >> 4, sl = i & 15;
    if (sl >= 1 && sl <= (int)s_tl[m * TL]) {
      int ai = s_tl[i];
      unsigned d = (unsigned)(ai - a0);
      if (d < 256u) atomicOr(&s_m[d], 1ull << m);
    }
  }
  __syncthreads();

  const int a = a0 + tid;
  if (a >= NA) return;

  const int ia = b * NA + a;
  unsigned long long msk = s_m[tid];
  int cnt = __popcll(msk);
  int chosen = 0; float ovv = 0.f, av = 0.f, fg = 0.f;

  if (cnt > 0) {
    fg = 1.f;
    float4 p = *(const float4*)(pd_bb + (size_t)ia * 4);
    float pa = fmaxf(p.z - p.x, 0.f) * fmaxf(p.w - p.y, 0.f);
    if (cnt == 1) {
      chosen = __ffsll(msk) - 1;
      ovv = iou1(s_g[chosen], s_ga[chosen], p, pa);
    } else {
      float best = -1.f; int bmx = 0;
      for (int m = 0; m < NM; m++) {
        float v = iou1(s_g[m], s_ga[m], p, pa);
        if (v > best) { best = v; bmx = m; }   // strict >: first max (jnp.argmax)
      }
      chosen = bmx; ovv = best;
    }
    float sc = pro[(size_t)ia * NPRO + s_lab[chosen]];
    float o2 = ovv * ovv;
    av = sc * (o2 * o2 * o2);
    atomicMax(&posA[b * NM + chosen], __float_as_uint(av));  // values >= 0
    atomicMax(&posO[b * NM + chosen], __float_as_uint(ovv));
  }
  tgi[ia] = chosen; fgo[ia] = fg; avo[ia] = av;
}

// ---------------- kC: gather targets + write all outputs (nontemporal) ----------------
__global__ __launch_bounds__(256) void kC(
    const int* __restrict__ gt_pro, const int* __restrict__ gt_alp,
    const int* __restrict__ gt_ads, const float* __restrict__ gt_bb,
    const float* __restrict__ gt_cor,
    const unsigned* __restrict__ posA, const unsigned* __restrict__ posO,
    const int* __restrict__ tgi, const float* __restrict__ fgi,
    const float* __restrict__ avi, float* __restrict__ out)
{
  __shared__ int s_tp[256], s_ta[256];
  __shared__ int s_td[5][256];
  __shared__ float s_pv[256], s_fg[256];

  const int b = blockIdx.y;
  const int a0 = blockIdx.x * 256;
  const int tid = threadIdx.x;
  const int na = min(256, NA - a0);
  const int a = a0 + tid;

  if (a < NA) {
    const int ia = b * NA + a;
    const int g = tgi[ia];
    const float fg = fgi[ia];
    float no = 0.f;
    if (fg > 0.f) {
      no = avi[ia] * __uint_as_float(posO[b * NM + g]) /
           (__uint_as_float(posA[b * NM + g]) + FEPS);
    }
    const int gi = b * NM + g;
    const int tp = gt_pro[gi], ta = gt_alp[gi];
    s_tp[tid] = tp; s_ta[tid] = ta; s_pv[tid] = no; s_fg[tid] = fg;
    nt1(out + OFF0 + ia, (float)tp);
    nt1(out + OFF1 + ia, (float)ta);
#pragma unroll
    for (int k = 0; k < 5; k++) {
      int td = gt_ads[(size_t)gi * 5 + k];
      s_td[k][tid] = td;
      nt1(out + OFF2 + (size_t)k * (BS * NA) + ia, (float)td);
    }
    float4 bb = *(const float4*)(gt_bb + (size_t)gi * 4);
    nt4(out + OFF3 + (size_t)ia * 4, bb.x, bb.y, bb.z, bb.w);
    float4 c0 = *(const float4*)(gt_cor + (size_t)gi * 8);
    float4 c1 = *(const float4*)(gt_cor + (size_t)gi * 8 + 4);
    nt4(out + OFF4 + (size_t)ia * 8, c0.x, c0.y, c0.z, c0.w);
    nt4(out + OFF4 + (size_t)ia * 8 + 4, c1.x, c1.y, c1.z, c1.w);
    nt1(out + OFF8 + ia, fg);
  }
  __syncthreads();

  // pro_scores one-hot * norm
  {
    float* dst = out + OFF5 + ((size_t)b * NA + a0) * NPRO;
    const int n = na * NPRO;
    for (int e4 = tid * 4; e4 < n; e4 += 1024) {
      float vv[4];
#pragma unroll
      for (int j = 0; j < 4; j++) {
        int e = e4 + j; int al = e / NPRO; int c = e - al * NPRO;
        vv[j] = (c == s_tp[al]) ? s_pv[al] : 0.f;
      }
      nt4(dst + e4, vv[0], vv[1], vv[2], vv[3]);
    }
  }
  // alp_scores one-hot * fg
  {
    float* dst = out + OFF6 + ((size_t)b * NA + a0) * NALP;
    const int n = na * NALP;
    for (int e4 = tid * 4; e4 < n; e4 += 1024) {
      float vv[4];
#pragma unroll
      for (int j = 0; j < 4; j++) {
        int e = e4 + j; int al = e / NALP; int c = e - al * NALP;
        vv[j] = (c == s_ta[al]) ? s_fg[al] : 0.f;
      }
      nt4(dst + e4, vv[0], vv[1], vv[2], vv[3]);
    }
  }
  // ads_scores one-hot * fg, 5 heads
#pragma unroll
  for (int k = 0; k < 5; k++) {
    float* dst = out + OFF7 + (size_t)k * ((size_t)BS * NA * NADS) +
                 ((size_t)b * NA + a0) * NADS;
    const int n = na * NADS;
    for (int e4 = tid * 4; e4 < n; e4 += 1024) {
      float vv[4];
#pragma unroll
      for (int j = 0; j < 4; j++) {
        int e = e4 + j; int al = e / NADS; int c = e - al * NADS;
        vv[j] = (c == s_td[k][al]) ? s_fg[al] : 0.f;
      }
      nt4(dst + e4, vv[0], vv[1], vv[2], vv[3]);
    }
  }
}

extern "C" void kernel_launch(void* const* d_in, const int* in_sizes, int n_in,
                              void* d_out, int out_size, void* d_ws, size_t ws_size,
                              hipStream_t stream) {
  const float* pd_pro  = (const float*)d_in[0];
  const float* pd_bb   = (const float*)d_in[3];
  const float* anc     = (const float*)d_in[5];
  const int*   gt_pro  = (const int*)d_in[6];
  const int*   gt_alp  = (const int*)d_in[7];
  const int*   gt_ads  = (const int*)d_in[8];
  const float* gt_bb   = (const float*)d_in[9];
  const float* gt_cor  = (const float*)d_in[10];
  const float* mask_gt = (const float*)d_in[11];
  float* out = (float*)d_out;

  char* ws = (char*)d_ws;
  short*    tlist = (short*)(ws);                 // 2048*16*2 = 65,536 B
  unsigned* posA  = (unsigned*)(ws + 65536);      // 2048*4
  unsigned* posO  = (unsigned*)(ws + 73728);      // 2048*4
  int*      tgi   = (int*)     (ws + 81920);      // 268800*4
  float*    fgo   = (float*)   (ws + 1157120);    // 268800*4
  float*    avo   = (float*)   (ws + 2232320);    // 268800*4 (end 3,307,520)

  kA<<<BS * NM, 256, 0, stream>>>(pd_pro, pd_bb, anc, gt_pro, gt_bb, mask_gt,
                                  tlist, posA, posO);
  dim3 gridBC((NA + 255) / 256, BS);
  kB<<<gridBC, 256, 0, stream>>>(pd_pro, pd_bb, gt_pro, gt_bb, tlist,
                                 posA, posO, tgi, fgo, avo);
  kC<<<gridBC, 256, 0, stream>>>(gt_pro, gt_alp, gt_ads, gt_bb, gt_cor,
                                 posA, posO, tgi, fgo, avo, out);
  // INSTRUMENTATION (remove next round): duplicate kC launch. kC is idempotent
  // (reads only ws + gt tables, rewrites identical values), so this measures
  // kC's exact duration as dur_r3 - dur_r4 once the dup is removed.
  kC<<<gridBC, 256, 0, stream>>>(gt_pro, gt_alp, gt_ads, gt_bb, gt_cor,
                                 posA, posO, tgi, fgo, avo, out);
}

// Round 4
// 135.461 us; speedup vs baseline: 1.4994x; 1.4994x over previous
//
#include <hip/hip_runtime.h>
#include <cstdint>
#include <cstddef>

#define BS 32
#define NA 8400
#define NM 64
#define NPRO 31
#define NALP 24
#define NADS 37
#define TOPK 13
#define FEPS 1e-9f
#define WORDS 264   // ceil(8400/32)=263, padded
#define CAP 1024    // compact positive-metric list capacity (expected max ~400)
#define TL 16       // per-(b,m) topk list slots: [0]=count, [1..13]=anchor ids

// output offsets (floats), concatenated in reference return order
#define OFF0 0L          // target_pro      (32,8400)
#define OFF1 268800L     // target_alp      (32,8400)
#define OFF2 537600L     // target_ad0_4    (5,32,8400)
#define OFF3 1881600L    // target_bboxes   (32,8400,4)
#define OFF4 2956800L    // target_corners  (32,8400,8)
#define OFF5 5107200L    // pro_scores      (32,8400,31)
#define OFF6 13440000L   // alp_scores      (32,8400,24)
#define OFF7 19891200L   // ads_scores      (5,32,8400,37)
#define OFF8 69619200L   // fg_mask         (32,8400)

typedef float f4_t __attribute__((ext_vector_type(4)));

__device__ __forceinline__ void nt4(float* p, float a, float b, float c, float d) {
  f4_t v = {a, b, c, d};
  __builtin_nontemporal_store(v, (f4_t*)p);
}
__device__ __forceinline__ void nt1(float* p, float v) {
  __builtin_nontemporal_store(v, p);
}

__device__ __forceinline__ float iou1(float4 g, float ga, float4 p, float pa) {
  float iw = fmaxf(fminf(g.z, p.z) - fmaxf(g.x, p.x), 0.f);
  float ih = fmaxf(fminf(g.w, p.w) - fmaxf(g.y, p.y), 0.f);
  float inter = iw * ih;
  return inter / (ga + pa - inter + FEPS);
}

// ---------------- kA: per-(b,m) sparse metrics + exact top-13 -> compact list ----------------
__global__ __launch_bounds__(256) void kA(
    const float* __restrict__ pro, const float* __restrict__ pd_bb,
    const float* __restrict__ anc, const int* __restrict__ gt_pro,
    const float* __restrict__ gt_bb, const float* __restrict__ mask_gt,
    short* __restrict__ tlist, unsigned* __restrict__ posA,
    unsigned* __restrict__ posO)
{
  __shared__ unsigned s_in[WORDS];   // in-box bits
  __shared__ unsigned s_pos[WORDS];  // positive-metric bits
  __shared__ float s_cv[CAP];
  __shared__ int   s_ci[CAP];
  __shared__ int   s_cnt;

  const int bm = blockIdx.x;
  const int b = bm >> 6;
  const int tid = threadIdx.x;

  if (tid == 0) { posA[bm] = 0u; posO[bm] = 0u; }

  short* tl = tlist + bm * TL;
  if (!(mask_gt[bm] > 0.f)) {        // invalid gt -> no selections (counts>1 trick)
    if (tid == 0) tl[0] = 0;
    return;
  }

  for (int w = tid; w < WORDS; w += 256) { s_in[w] = 0u; s_pos[w] = 0u; }
  if (tid == 0) s_cnt = 0;
  __syncthreads();

  const float4 g = *(const float4*)(gt_bb + (size_t)bm * 4);
  const int label = gt_pro[bm];
  const float ga = fmaxf(g.z - g.x, 0.f) * fmaxf(g.w - g.y, 0.f);
  const float* pb = pd_bb + (size_t)b * NA * 4;
  const float* ps = pro + (size_t)b * NA * NPRO + label;

  for (int a = tid; a < NA; a += 256) {
    float2 ap = *(const float2*)(anc + 2 * a);
    float din = fminf(fminf(ap.x - g.x, ap.y - g.y), fminf(g.z - ap.x, g.w - ap.y));
    if (din > FEPS) {
      atomicOr(&s_in[a >> 5], 1u << (a & 31));
      float4 p = *(const float4*)(pb + (size_t)a * 4);
      float pa = fmaxf(p.z - p.x, 0.f) * fmaxf(p.w - p.y, 0.f);
      float iou = iou1(g, ga, p, pa);
      float i2 = iou * iou;
      float met = ps[(size_t)a * NPRO] * (i2 * i2 * i2);
      if (met > 0.f) {
        atomicOr(&s_pos[a >> 5], 1u << (a & 31));
        int pidx = atomicAdd(&s_cnt, 1);
        if (pidx < CAP) { s_cv[pidx] = met; s_ci[pidx] = a; }
      }
    }
  }
  __syncthreads();

  const int P = min(s_cnt, CAP);
  if (tid < 64) {
    // each lane owns entries tid, tid+64, ... in registers
    float lv[16]; int li[16];
#pragma unroll
    for (int e = 0; e < 16; e++) {
      int p = tid + e * 64;
      bool ok = p < P;
      lv[e] = ok ? s_cv[p] : -1.f;
      li[e] = ok ? s_ci[p] : NA;
    }
    const int nsel = min(P, TOPK);
    for (int k = 0; k < nsel; k++) {
      float bv = -1.f; int bi = NA;
#pragma unroll
      for (int e = 0; e < 16; e++)
        if (lv[e] > bv || (lv[e] == bv && li[e] < bi)) { bv = lv[e]; bi = li[e]; }
      for (int s = 1; s < 64; s <<= 1) {
        float ov = __shfl_xor(bv, s);
        int   oi = __shfl_xor(bi, s);
        if (ov > bv || (ov == bv && oi < bi)) { bv = ov; bi = oi; }
      }
#pragma unroll
      for (int e = 0; e < 16; e++) if (li[e] == bi) lv[e] = -1.f;  // clear winner
      if (tid == 0) tl[1 + k] = (short)bi;
    }
    if (tid == 0) {
      int cnt = nsel;
      if (P < TOPK) {
        // fill remaining slots with lowest-index zero-metric anchors (tie at 0),
        // keeping only in-box ones (mask_in AND)
        int need = TOPK - P;
        for (int a = 0; a < NA && need > 0; a++) {
          if (!((s_pos[a >> 5] >> (a & 31)) & 1u)) {
            need--;
            if ((s_in[a >> 5] >> (a & 31)) & 1u) tl[1 + cnt++] = (short)a;
          }
        }
      }
      tl[0] = (short)cnt;
    }
  }
}

// ---------------- kB: per-anchor resolve from compact lists ----------------
__global__ __launch_bounds__(256) void kB(
    const float* __restrict__ pro, const float* __restrict__ pd_bb,
    const int* __restrict__ gt_pro, const float* __restrict__ gt_bb,
    const short* __restrict__ tlist,
    unsigned* __restrict__ posA, unsigned* __restrict__ posO,
    int* __restrict__ tgi, float* __restrict__ fgo, float* __restrict__ avo)
{
  __shared__ float4 s_g[NM];
  __shared__ float s_ga[NM];
  __shared__ int s_lab[NM];
  __shared__ unsigned long long s_m[256];
  __shared__ short s_tl[NM * TL];

  const int b = blockIdx.y;
  const int a0 = blockIdx.x << 8;
  const int tid = threadIdx.x;

  s_m[tid] = 0ull;
  if (tid < NM) {
    float4 gg = *(const float4*)(gt_bb + (size_t)(b * NM + tid) * 4);
    s_g[tid] = gg;
    s_ga[tid] = fmaxf(gg.z - gg.x, 0.f) * fmaxf(gg.w - gg.y, 0.f);
    s_lab[tid] = gt_pro[b * NM + tid];
  }
  for (int i = tid; i < NM * TL / 2; i += 256)       // 512 ints = 1024 shorts
    ((int*)s_tl)[i] = ((const int*)(tlist + (size_t)b * NM * TL))[i];
  __syncthreads();

  for (int i = tid; i < NM * TL; i += 256) {
    int m = i >> 4, sl = i & 15;
    if (sl >= 1 && sl <= (int)s_tl[m * TL]) {
      int ai = s_tl[i];
      unsigned d = (unsigned)(ai - a0);
      if (d < 256u) atomicOr(&s_m[d], 1ull << m);
    }
  }
  __syncthreads();

  const int a = a0 + tid;
  if (a >= NA) return;

  const int ia = b * NA + a;
  unsigned long long msk = s_m[tid];
  int cnt = __popcll(msk);
  int chosen = 0; float ovv = 0.f, av = 0.f, fg = 0.f;

  if (cnt > 0) {
    fg = 1.f;
    float4 p = *(const float4*)(pd_bb + (size_t)ia * 4);
    float pa = fmaxf(p.z - p.x, 0.f) * fmaxf(p.w - p.y, 0.f);
    if (cnt == 1) {
      chosen = __ffsll(msk) - 1;
      ovv = iou1(s_g[chosen], s_ga[chosen], p, pa);
    } else {
      float best = -1.f; int bmx = 0;
      for (int m = 0; m < NM; m++) {
        float v = iou1(s_g[m], s_ga[m], p, pa);
        if (v > best) { best = v; bmx = m; }   // strict >: first max (jnp.argmax)
      }
      chosen = bmx; ovv = best;
    }
    float sc = pro[(size_t)ia * NPRO + s_lab[chosen]];
    float o2 = ovv * ovv;
    av = sc * (o2 * o2 * o2);
    atomicMax(&posA[b * NM + chosen], __float_as_uint(av));  // values >= 0
    atomicMax(&posO[b * NM + chosen], __float_as_uint(ovv));
  }
  tgi[ia] = chosen; fgo[ia] = fg; avo[ia] = av;
}

// ---------------- kC: gather targets + write all outputs (nontemporal) ----------------
__global__ __launch_bounds__(256) void kC(
    const int* __restrict__ gt_pro, const int* __restrict__ gt_alp,
    const int* __restrict__ gt_ads, const float* __restrict__ gt_bb,
    const float* __restrict__ gt_cor,
    const unsigned* __restrict__ posA, const unsigned* __restrict__ posO,
    const int* __restrict__ tgi, const float* __restrict__ fgi,
    const float* __restrict__ avi, float* __restrict__ out)
{
  __shared__ int s_tp[256], s_ta[256];
  __shared__ int s_td[5][256];
  __shared__ float s_pv[256], s_fg[256];

  const int b = blockIdx.y;
  const int a0 = blockIdx.x * 256;
  const int tid = threadIdx.x;
  const int na = min(256, NA - a0);
  const int a = a0 + tid;

  if (a < NA) {
    const int ia = b * NA + a;
    const int g = tgi[ia];
    const float fg = fgi[ia];
    float no = 0.f;
    if (fg > 0.f) {
      no = avi[ia] * __uint_as_float(posO[b * NM + g]) /
           (__uint_as_float(posA[b * NM + g]) + FEPS);
    }
    const int gi = b * NM + g;
    const int tp = gt_pro[gi], ta = gt_alp[gi];
    s_tp[tid] = tp; s_ta[tid] = ta; s_pv[tid] = no; s_fg[tid] = fg;
    nt1(out + OFF0 + ia, (float)tp);
    nt1(out + OFF1 + ia, (float)ta);
#pragma unroll
    for (int k = 0; k < 5; k++) {
      int td = gt_ads[(size_t)gi * 5 + k];
      s_td[k][tid] = td;
      nt1(out + OFF2 + (size_t)k * (BS * NA) + ia, (float)td);
    }
    float4 bb = *(const float4*)(gt_bb + (size_t)gi * 4);
    nt4(out + OFF3 + (size_t)ia * 4, bb.x, bb.y, bb.z, bb.w);
    float4 c0 = *(const float4*)(gt_cor + (size_t)gi * 8);
    float4 c1 = *(const float4*)(gt_cor + (size_t)gi * 8 + 4);
    nt4(out + OFF4 + (size_t)ia * 8, c0.x, c0.y, c0.z, c0.w);
    nt4(out + OFF4 + (size_t)ia * 8 + 4, c1.x, c1.y, c1.z, c1.w);
    nt1(out + OFF8 + ia, fg);
  }
  __syncthreads();

  // pro_scores one-hot * norm
  {
    float* dst = out + OFF5 + ((size_t)b * NA + a0) * NPRO;
    const int n = na * NPRO;
    for (int e4 = tid * 4; e4 < n; e4 += 1024) {
      float vv[4];
#pragma unroll
      for (int j = 0; j < 4; j++) {
        int e = e4 + j; int al = e / NPRO; int c = e - al * NPRO;
        vv[j] = (c == s_tp[al]) ? s_pv[al] : 0.f;
      }
      nt4(dst + e4, vv[0], vv[1], vv[2], vv[3]);
    }
  }
  // alp_scores one-hot * fg
  {
    float* dst = out + OFF6 + ((size_t)b * NA + a0) * NALP;
    const int n = na * NALP;
    for (int e4 = tid * 4; e4 < n; e4 += 1024) {
      float vv[4];
#pragma unroll
      for (int j = 0; j < 4; j++) {
        int e = e4 + j; int al = e / NALP; int c = e - al * NALP;
        vv[j] = (c == s_ta[al]) ? s_fg[al] : 0.f;
      }
      nt4(dst + e4, vv[0], vv[1], vv[2], vv[3]);
    }
  }
  // ads_scores one-hot * fg, 5 heads
#pragma unroll
  for (int k = 0; k < 5; k++) {
    float* dst = out + OFF7 + (size_t)k * ((size_t)BS * NA * NADS) +
                 ((size_t)b * NA + a0) * NADS;
    const int n = na * NADS;
    for (int e4 = tid * 4; e4 < n; e4 += 1024) {
      float vv[4];
#pragma unroll
      for (int j = 0; j < 4; j++) {
        int e = e4 + j; int al = e / NADS; int c = e - al * NADS;
        vv[j] = (c == s_td[k][al]) ? s_fg[al] : 0.f;
      }
      nt4(dst + e4, vv[0], vv[1], vv[2], vv[3]);
    }
  }
}

extern "C" void kernel_launch(void* const* d_in, const int* in_sizes, int n_in,
                              void* d_out, int out_size, void* d_ws, size_t ws_size,
                              hipStream_t stream) {
  const float* pd_pro  = (const float*)d_in[0];
  const float* pd_bb   = (const float*)d_in[3];
  const float* anc     = (const float*)d_in[5];
  const int*   gt_pro  = (const int*)d_in[6];
  const int*   gt_alp  = (const int*)d_in[7];
  const int*   gt_ads  = (const int*)d_in[8];
  const float* gt_bb   = (const float*)d_in[9];
  const float* gt_cor  = (const float*)d_in[10];
  const float* mask_gt = (const float*)d_in[11];
  float* out = (float*)d_out;

  char* ws = (char*)d_ws;
  short*    tlist = (short*)(ws);                 // 2048*16*2 = 65,536 B
  unsigned* posA  = (unsigned*)(ws + 65536);      // 2048*4
  unsigned* posO  = (unsigned*)(ws + 73728);      // 2048*4
  int*      tgi   = (int*)     (ws + 81920);      // 268800*4
  float*    fgo   = (float*)   (ws + 1157120);    // 268800*4
  float*    avo   = (float*)   (ws + 2232320);    // 268800*4 (end 3,307,520)

  kA<<<BS * NM, 256, 0, stream>>>(pd_pro, pd_bb, anc, gt_pro, gt_bb, mask_gt,
                                  tlist, posA, posO);
  dim3 gridBC((NA + 255) / 256, BS);
  kB<<<gridBC, 256, 0, stream>>>(pd_pro, pd_bb, gt_pro, gt_bb, tlist,
                                 posA, posO, tgi, fgo, avo);
  kC<<<gridBC, 256, 0, stream>>>(gt_pro, gt_alp, gt_ads, gt_bb, gt_cor,
                                 posA, posO, tgi, fgo, avo, out);
  // dup-kC instrumentation removed: kC_nt = dur_r3 (203.1) - dur_r4
}

// Round 5
// 120.981 us; speedup vs baseline: 1.6789x; 1.1197x over previous
//
#include <hip/hip_runtime.h>
#include <cstdint>
#include <cstddef>

#define BS 32
#define NA 8400
#define NM 64
#define NPRO 31
#define NALP 24
#define NADS 37
#define TOPK 13
#define FEPS 1e-9f
#define WORDS 264   // ceil(8400/32)=263, padded (ballot writes words 0..263)
#define CAP 512     // compact positive-metric list capacity (expected max ~300)
#define TL 16       // per-(b,m) topk list slots: [0]=count, [1..13]=anchor ids

// output offsets (floats), concatenated in reference return order
#define OFF0 0L          // target_pro      (32,8400)
#define OFF1 268800L     // target_alp      (32,8400)
#define OFF2 537600L     // target_ad0_4    (5,32,8400)
#define OFF3 1881600L    // target_bboxes   (32,8400,4)
#define OFF4 2956800L    // target_corners  (32,8400,8)
#define OFF5 5107200L    // pro_scores      (32,8400,31)
#define OFF6 13440000L   // alp_scores      (32,8400,24)
#define OFF7 19891200L   // ads_scores      (5,32,8400,37)
#define OFF8 69619200L   // fg_mask         (32,8400)

__device__ __forceinline__ float iou1(float4 g, float ga, float4 p, float pa) {
  float iw = fmaxf(fminf(g.z, p.z) - fmaxf(g.x, p.x), 0.f);
  float ih = fmaxf(fminf(g.w, p.w) - fmaxf(g.y, p.y), 0.f);
  float inter = iw * ih;
  return inter / (ga + pa - inter + FEPS);
}

// ---------------- kA: per-(b,m) ballot-scan + exact top-13 -> compact list ----------------
__global__ __launch_bounds__(256) void kA(
    const float* __restrict__ pro, const float* __restrict__ pd_bb,
    const float* __restrict__ anc, const int* __restrict__ gt_pro,
    const float* __restrict__ gt_bb, const float* __restrict__ mask_gt,
    short* __restrict__ tlist, unsigned* __restrict__ posA,
    unsigned* __restrict__ posO)
{
  __shared__ unsigned s_in[WORDS];   // in-box bits (written via ballot, no init)
  __shared__ unsigned s_pos[WORDS];  // positive-metric bits
  __shared__ float s_cv[CAP];
  __shared__ int   s_ci[CAP];
  __shared__ int   s_cnt;

  const int bm = blockIdx.x;
  const int b = bm >> 6;
  const int tid = threadIdx.x;
  const int lane = tid & 63;

  if (tid == 0) { posA[bm] = 0u; posO[bm] = 0u; s_cnt = 0; }

  short* tl = tlist + bm * TL;
  if (!(mask_gt[bm] > 0.f)) {        // invalid gt -> no selections (counts>1 trick)
    if (tid == 0) tl[0] = 0;
    return;
  }
  __syncthreads();

  const float4 g = *(const float4*)(gt_bb + (size_t)bm * 4);
  const int label = gt_pro[bm];
  const float ga = fmaxf(g.z - g.x, 0.f) * fmaxf(g.w - g.y, 0.f);
  const float* pb = pd_bb + (size_t)b * NA * 4;
  const float* ps = pro + (size_t)b * NA * NPRO + label;

  for (int j = 0; j < (NA + 255) / 256; j++) {
    const int a = j * 256 + tid;
    bool inb = false, posb = false; float met = 0.f;
    if (a < NA) {
      float2 ap = *(const float2*)(anc + 2 * a);
      float din = fminf(fminf(ap.x - g.x, ap.y - g.y), fminf(g.z - ap.x, g.w - ap.y));
      if (din > FEPS) {
        inb = true;
        float4 p = *(const float4*)(pb + (size_t)a * 4);
        float pa = fmaxf(p.z - p.x, 0.f) * fmaxf(p.w - p.y, 0.f);
        float iou = iou1(g, ga, p, pa);
        float i2 = iou * iou;
        met = ps[(size_t)a * NPRO] * (i2 * i2 * i2);
        posb = met > 0.f;
      }
    }
    unsigned long long bin  = __ballot(inb);
    unsigned long long bpos = __ballot(posb);
    if (lane == 0) {
      int w0 = (j << 3) + ((tid >> 6) << 1);
      s_in[w0]      = (unsigned)bin;
      s_in[w0 + 1]  = (unsigned)(bin >> 32);
      s_pos[w0]     = (unsigned)bpos;
      s_pos[w0 + 1] = (unsigned)(bpos >> 32);
    }
    if (bpos) {                       // wave-uniform; rare (few positives per gt)
      int base = 0;
      if (lane == 0) base = atomicAdd(&s_cnt, __popcll(bpos));
      base = __shfl(base, 0);
      if (posb) {
        int idx = base + __popcll(bpos & ((1ull << lane) - 1ull));
        if (idx < CAP) { s_cv[idx] = met; s_ci[idx] = a; }
      }
    }
  }
  __syncthreads();

  const int P = min(s_cnt, CAP);
  if (tid < 64) {
    // each lane owns entries tid, tid+64, ... in registers (CAP/64 = 8)
    float lv[8]; int li[8];
#pragma unroll
    for (int e = 0; e < 8; e++) {
      int p = tid + e * 64;
      bool ok = p < P;
      lv[e] = ok ? s_cv[p] : -1.f;
      li[e] = ok ? s_ci[p] : NA;
    }
    const int nsel = min(P, TOPK);
    for (int k = 0; k < nsel; k++) {
      float bv = -1.f; int bi = NA;
#pragma unroll
      for (int e = 0; e < 8; e++)
        if (lv[e] > bv || (lv[e] == bv && li[e] < bi)) { bv = lv[e]; bi = li[e]; }
      for (int s = 1; s < 64; s <<= 1) {
        float ov = __shfl_xor(bv, s);
        int   oi = __shfl_xor(bi, s);
        if (ov > bv || (ov == bv && oi < bi)) { bv = ov; bi = oi; }
      }
#pragma unroll
      for (int e = 0; e < 8; e++) if (li[e] == bi) lv[e] = -1.f;  // clear winner
      if (tid == 0) tl[1 + k] = (short)bi;
    }
    if (tid == 0) {
      int cnt = nsel;
      if (P < TOPK) {
        // fill remaining slots with lowest-index zero-metric anchors (tie at 0),
        // keeping only in-box ones (mask_in AND); exits after ~13 iterations
        int need = TOPK - P;
        for (int a = 0; a < NA && need > 0; a++) {
          if (!((s_pos[a >> 5] >> (a & 31)) & 1u)) {
            need--;
            if ((s_in[a >> 5] >> (a & 31)) & 1u) tl[1 + cnt++] = (short)a;
          }
        }
      }
      tl[0] = (short)cnt;
    }
  }
}

// ---------------- kB: per-anchor resolve from compact lists ----------------
__global__ __launch_bounds__(256) void kB(
    const float* __restrict__ pro, const float* __restrict__ pd_bb,
    const int* __restrict__ gt_pro, const float* __restrict__ gt_bb,
    const short* __restrict__ tlist,
    unsigned* __restrict__ posA, unsigned* __restrict__ posO,
    int* __restrict__ tgi, float* __restrict__ fgo, float* __restrict__ avo)
{
  __shared__ float4 s_g[NM];
  __shared__ float s_ga[NM];
  __shared__ int s_lab[NM];
  __shared__ unsigned long long s_m[256];
  __shared__ short s_tl[NM * TL];

  const int b = blockIdx.y;
  const int a0 = blockIdx.x << 8;
  const int tid = threadIdx.x;

  s_m[tid] = 0ull;
  if (tid < NM) {
    float4 gg = *(const float4*)(gt_bb + (size_t)(b * NM + tid) * 4);
    s_g[tid] = gg;
    s_ga[tid] = fmaxf(gg.z - gg.x, 0.f) * fmaxf(gg.w - gg.y, 0.f);
    s_lab[tid] = gt_pro[b * NM + tid];
  }
  for (int i = tid; i < NM * TL / 2; i += 256)       // 512 ints = 1024 shorts
    ((int*)s_tl)[i] = ((const int*)(tlist + (size_t)b * NM * TL))[i];
  __syncthreads();

  for (int i = tid; i < NM * TL; i += 256) {
    int m = i >> 4, sl = i & 15;
    if (sl >= 1 && sl <= (int)s_tl[m * TL]) {
      int ai = s_tl[i];
      unsigned d = (unsigned)(ai - a0);
      if (d < 256u) atomicOr(&s_m[d], 1ull << m);
    }
  }
  __syncthreads();

  const int a = a0 + tid;
  if (a >= NA) return;

  const int ia = b * NA + a;
  unsigned long long msk = s_m[tid];
  int cnt = __popcll(msk);
  int chosen = 0; float ovv = 0.f, av = 0.f, fg = 0.f;

  if (cnt > 0) {
    fg = 1.f;
    float4 p = *(const float4*)(pd_bb + (size_t)ia * 4);
    float pa = fmaxf(p.z - p.x, 0.f) * fmaxf(p.w - p.y, 0.f);
    if (cnt == 1) {
      chosen = __ffsll(msk) - 1;
      ovv = iou1(s_g[chosen], s_ga[chosen], p, pa);
    } else {
      float best = -1.f; int bmx = 0;
      for (int m = 0; m < NM; m++) {
        float v = iou1(s_g[m], s_ga[m], p, pa);
        if (v > best) { best = v; bmx = m; }   // strict >: first max (jnp.argmax)
      }
      chosen = bmx; ovv = best;
    }
    float sc = pro[(size_t)ia * NPRO + s_lab[chosen]];
    float o2 = ovv * ovv;
    av = sc * (o2 * o2 * o2);
    atomicMax(&posA[b * NM + chosen], __float_as_uint(av));  // values >= 0
    atomicMax(&posO[b * NM + chosen], __float_as_uint(ovv));
  }
  tgi[ia] = chosen; fgo[ia] = fg; avo[ia] = av;
}

// ---------------- kC: gather targets + write all outputs (64-anchor tiles) ----------------
__global__ __launch_bounds__(64) void kC(
    const int* __restrict__ gt_pro, const int* __restrict__ gt_alp,
    const int* __restrict__ gt_ads, const float* __restrict__ gt_bb,
    const float* __restrict__ gt_cor,
    const unsigned* __restrict__ posA, const unsigned* __restrict__ posO,
    const int* __restrict__ tgi, const float* __restrict__ fgi,
    const float* __restrict__ avi, float* __restrict__ out)
{
  __shared__ int s_tp[64], s_ta[64];
  __shared__ int s_td[5][64];
  __shared__ float s_pv[64], s_fg[64];

  const int b = blockIdx.y;
  const int a0 = blockIdx.x * 64;
  const int tid = threadIdx.x;
  const int na = min(64, NA - a0);
  const int a = a0 + tid;

  if (tid < na) {
    const int ia = b * NA + a;
    const int g = tgi[ia];
    const float fg = fgi[ia];
    float no = 0.f;
    if (fg > 0.f) {
      no = avi[ia] * __uint_as_float(posO[b * NM + g]) /
           (__uint_as_float(posA[b * NM + g]) + FEPS);
    }
    const int gi = b * NM + g;
    const int tp = gt_pro[gi], ta = gt_alp[gi];
    s_tp[tid] = tp; s_ta[tid] = ta; s_pv[tid] = no; s_fg[tid] = fg;
    out[OFF0 + ia] = (float)tp;
    out[OFF1 + ia] = (float)ta;
#pragma unroll
    for (int k = 0; k < 5; k++) {
      int td = gt_ads[(size_t)gi * 5 + k];
      s_td[k][tid] = td;
      out[OFF2 + (size_t)k * (BS * NA) + ia] = (float)td;
    }
    float4 bb = *(const float4*)(gt_bb + (size_t)gi * 4);
    *(float4*)(out + OFF3 + (size_t)ia * 4) = bb;
    float4 c0 = *(const float4*)(gt_cor + (size_t)gi * 8);
    float4 c1 = *(const float4*)(gt_cor + (size_t)gi * 8 + 4);
    *(float4*)(out + OFF4 + (size_t)ia * 8) = c0;
    *(float4*)(out + OFF4 + (size_t)ia * 8 + 4) = c1;
    out[OFF8 + ia] = fg;
  }
  __syncthreads();

  // pro_scores one-hot * norm   (na*31 floats, div by 4)
  {
    float* dst = out + OFF5 + ((size_t)b * NA + a0) * NPRO;
    const int n = na * NPRO;
    for (int e4 = tid * 4; e4 < n; e4 += 256) {
      float vv[4];
#pragma unroll
      for (int j = 0; j < 4; j++) {
        int e = e4 + j; int al = e / NPRO; int c = e - al * NPRO;
        vv[j] = (c == s_tp[al]) ? s_pv[al] : 0.f;
      }
      *(float4*)(dst + e4) = make_float4(vv[0], vv[1], vv[2], vv[3]);
    }
  }
  // alp_scores one-hot * fg
  {
    float* dst = out + OFF6 + ((size_t)b * NA + a0) * NALP;
    const int n = na * NALP;
    for (int e4 = tid * 4; e4 < n; e4 += 256) {
      float vv[4];
#pragma unroll
      for (int j = 0; j < 4; j++) {
        int e = e4 + j; int al = e / NALP; int c = e - al * NALP;
        vv[j] = (c == s_ta[al]) ? s_fg[al] : 0.f;
      }
      *(float4*)(dst + e4) = make_float4(vv[0], vv[1], vv[2], vv[3]);
    }
  }
  // ads_scores one-hot * fg, 5 heads
#pragma unroll
  for (int k = 0; k < 5; k++) {
    float* dst = out + OFF7 + (size_t)k * ((size_t)BS * NA * NADS) +
                 ((size_t)b * NA + a0) * NADS;
    const int n = na * NADS;
    for (int e4 = tid * 4; e4 < n; e4 += 256) {
      float vv[4];
#pragma unroll
      for (int j = 0; j < 4; j++) {
        int e = e4 + j; int al = e / NADS; int c = e - al * NADS;
        vv[j] = (c == s_td[k][al]) ? s_fg[al] : 0.f;
      }
      *(float4*)(dst + e4) = make_float4(vv[0], vv[1], vv[2], vv[3]);
    }
  }
}

extern "C" void kernel_launch(void* const* d_in, const int* in_sizes, int n_in,
                              void* d_out, int out_size, void* d_ws, size_t ws_size,
                              hipStream_t stream) {
  const float* pd_pro  = (const float*)d_in[0];
  const float* pd_bb   = (const float*)d_in[3];
  const float* anc     = (const float*)d_in[5];
  const int*   gt_pro  = (const int*)d_in[6];
  const int*   gt_alp  = (const int*)d_in[7];
  const int*   gt_ads  = (const int*)d_in[8];
  const float* gt_bb   = (const float*)d_in[9];
  const float* gt_cor  = (const float*)d_in[10];
  const float* mask_gt = (const float*)d_in[11];
  float* out = (float*)d_out;

  char* ws = (char*)d_ws;
  short*    tlist = (short*)(ws);                 // 2048*16*2 = 65,536 B
  unsigned* posA  = (unsigned*)(ws + 65536);      // 2048*4
  unsigned* posO  = (unsigned*)(ws + 73728);      // 2048*4
  int*      tgi   = (int*)     (ws + 81920);      // 268800*4
  float*    fgo   = (float*)   (ws + 1157120);    // 268800*4
  float*    avo   = (float*)   (ws + 2232320);    // 268800*4 (end 3,307,520)

  kA<<<BS * NM, 256, 0, stream>>>(pd_pro, pd_bb, anc, gt_pro, gt_bb, mask_gt,
                                  tlist, posA, posO);
  dim3 gridB((NA + 255) / 256, BS);
  kB<<<gridB, 256, 0, stream>>>(pd_pro, pd_bb, gt_pro, gt_bb, tlist,
                                posA, posO, tgi, fgo, avo);
  dim3 gridC((NA + 63) / 64, BS);
  kC<<<gridC, 64, 0, stream>>>(gt_pro, gt_alp, gt_ads, gt_bb, gt_cor,
                               posA, posO, tgi, fgo, avo, out);
}